// Round 1
// baseline (226.421 us; speedup 1.0000x reference)
//
#include <hip/hip_runtime.h>
#include <math.h>

#define N_ROWS 2048
#define D_DIM  512
#define V_DIM  32000
#define K_TOP  16

// ---------------- Kernel A: per-row stats (bandwidth, sparse softmax, logsumexp) --------
__global__ __launch_bounds__(256) void k_rowstats(
    const float* __restrict__ hidden,
    const float* __restrict__ logits,
    const float* __restrict__ dist,
    const float* __restrict__ sh,
    const float* __restrict__ bwW,
    const float* __restrict__ bwb,
    float* __restrict__ sd_out,
    float* __restrict__ L_out)
{
  const int n   = blockIdx.x;
  const int tid = threadIdx.x;
  __shared__ float red[4];
  __shared__ float mred[4], sred[4];

  // ---- bandwidth dot: hidden . bwW[0:512] + mean_k(sh) . bwW[512:1024] ----
  float part = 0.0f;
  const float* hrow  = hidden + (size_t)n * D_DIM;
  const float* shrow = sh + (size_t)n * K_TOP * D_DIM;
  for (int d = tid; d < D_DIM; d += 256) {
    float msum = 0.0f;
#pragma unroll
    for (int k = 0; k < K_TOP; ++k) msum += shrow[k * D_DIM + d];
    part += hrow[d] * bwW[d] + (msum * (1.0f / 16.0f)) * bwW[D_DIM + d];
  }
#pragma unroll
  for (int off = 32; off > 0; off >>= 1) part += __shfl_down(part, off);
  if ((tid & 63) == 0) red[tid >> 6] = part;
  __syncthreads();
  if (tid == 0) {
    float dot = red[0] + red[1] + red[2] + red[3] + bwb[0];
    float bw  = 1.0f / (1.0f + __expf(-dot));
    float sc[K_TOP];
    float mx = -1e30f;
#pragma unroll
    for (int k = 0; k < K_TOP; ++k) {
      sc[k] = -dist[n * K_TOP + k] / bw;
      mx = fmaxf(mx, sc[k]);
    }
    float ssum = 0.0f;
#pragma unroll
    for (int k = 0; k < K_TOP; ++k) { sc[k] = __expf(sc[k] - mx); ssum += sc[k]; }
    float inv = 1.0f / ssum;
#pragma unroll
    for (int k = 0; k < K_TOP; ++k) sd_out[n * K_TOP + k] = sc[k] * inv;
  }

  // ---- online logsumexp over the 32000 logits (4 independent chains) ----
  const float4* lrow = (const float4*)(logits + (size_t)n * V_DIM);
  float m0 = -1e30f, m1 = -1e30f, m2 = -1e30f, m3 = -1e30f;
  float s0 = 0.f, s1 = 0.f, s2 = 0.f, s3 = 0.f;
  for (int i = tid; i < V_DIM / 4; i += 256) {
    float4 v = lrow[i];
    float t;
    t = fmaxf(m0, v.x); s0 = s0 * __expf(m0 - t) + __expf(v.x - t); m0 = t;
    t = fmaxf(m1, v.y); s1 = s1 * __expf(m1 - t) + __expf(v.y - t); m1 = t;
    t = fmaxf(m2, v.z); s2 = s2 * __expf(m2 - t) + __expf(v.z - t); m2 = t;
    t = fmaxf(m3, v.w); s3 = s3 * __expf(m3 - t) + __expf(v.w - t); m3 = t;
  }
  float M = fmaxf(fmaxf(m0, m1), fmaxf(m2, m3));
  float S = s0 * __expf(m0 - M) + s1 * __expf(m1 - M)
          + s2 * __expf(m2 - M) + s3 * __expf(m3 - M);
#pragma unroll
  for (int off = 32; off > 0; off >>= 1) {
    float M2 = __shfl_xor(M, off);
    float S2 = __shfl_xor(S, off);
    float Mn = fmaxf(M, M2);
    S = S * __expf(M - Mn) + S2 * __expf(M2 - Mn);
    M = Mn;
  }
  if ((tid & 63) == 0) { mred[tid >> 6] = M; sred[tid >> 6] = S; }
  __syncthreads();
  if (tid == 0) {
    float Mf = fmaxf(fmaxf(mred[0], mred[1]), fmaxf(mred[2], mred[3]));
    float Sf = sred[0] * __expf(mred[0] - Mf) + sred[1] * __expf(mred[1] - Mf)
             + sred[2] * __expf(mred[2] - Mf) + sred[3] * __expf(mred[3] - Mf);
    L_out[n] = Mf + logf(Sf);
  }
}

// ---------------- Kernel B: mixing-weight MLP (fp32 GEMM, 8 rows/block) ----------------
// 512 threads = 64 col-lanes (tx, 8 cols each) x 8 k-groups (tz, 128 k each).
__global__ __launch_bounds__(512) void k_mlp(
    const float* __restrict__ hidden,
    const float* __restrict__ sh,
    const float* __restrict__ sd,
    const float* __restrict__ W1,
    const float* __restrict__ b1,
    const float* __restrict__ W2,
    const float* __restrict__ b2,
    float* __restrict__ mix_out,
    float* __restrict__ l1m_out)
{
  __shared__ float smem[8192];            // 32 KB: A tile [8][1024], later 2-set reduce buf
  __shared__ float sd_l[8][K_TOP];
  const int tid = threadIdx.x;
  const int tx  = tid & 63;
  const int tz  = tid >> 6;
  const int r0  = blockIdx.x * 8;

  if (tid < 128) sd_l[tid >> 4][tid & 15] =
      sd[(size_t)(r0 + (tid >> 4)) * K_TOP + (tid & 15)];
  __syncthreads();

  // build A tile: cols 0..511 = hidden row, 512..1023 = sparse-prob-weighted merged
  {
    const int d = tid;  // 512 threads <-> 512 d's
#pragma unroll
    for (int r = 0; r < 8; ++r) {
      const int row = r0 + r;
      smem[r * 1024 + d] = hidden[(size_t)row * D_DIM + d];
      float acc = 0.0f;
#pragma unroll
      for (int k = 0; k < K_TOP; ++k)
        acc += sd_l[r][k] * sh[((size_t)row * K_TOP + k) * D_DIM + d];
      smem[r * 1024 + 512 + d] = acc;
    }
  }
  __syncthreads();

  float acc[8][8];
#pragma unroll
  for (int r = 0; r < 8; ++r)
#pragma unroll
    for (int j = 0; j < 8; ++j) acc[r][j] = 0.0f;

  const float4* A4 = (const float4*)smem;
  const float4* W4 = (const float4*)W1;
  const int kbase = tz * 128;
  for (int kk = 0; kk < 128; kk += 4) {
    const int k0 = kbase + kk;
    float4 a[8];
#pragma unroll
    for (int r = 0; r < 8; ++r) a[r] = A4[r * 256 + (k0 >> 2)];  // wave-uniform broadcast
#pragma unroll
    for (int dk = 0; dk < 4; ++dk) {
      const int k = k0 + dk;
      const float4 wlo = W4[k * 128 + tx * 2];
      const float4 whi = W4[k * 128 + tx * 2 + 1];
#pragma unroll
      for (int r = 0; r < 8; ++r) {
        const float av = (dk == 0) ? a[r].x : (dk == 1) ? a[r].y
                       : (dk == 2) ? a[r].z : a[r].w;
        acc[r][0] = fmaf(av, wlo.x, acc[r][0]);
        acc[r][1] = fmaf(av, wlo.y, acc[r][1]);
        acc[r][2] = fmaf(av, wlo.z, acc[r][2]);
        acc[r][3] = fmaf(av, wlo.w, acc[r][3]);
        acc[r][4] = fmaf(av, whi.x, acc[r][4]);
        acc[r][5] = fmaf(av, whi.y, acc[r][5]);
        acc[r][6] = fmaf(av, whi.z, acc[r][6]);
        acc[r][7] = fmaf(av, whi.w, acc[r][7]);
      }
    }
  }
  __syncthreads();   // all waves done reading the A tile; smem becomes reduce buffer

  // lane-stride-1 swizzle: value for col 8*tx+j stored at r*512 + tx + 64*j (conflict-free)
#define RED_WRITE(set) {                                                     \
  _Pragma("unroll") for (int r = 0; r < 8; ++r) {                            \
    _Pragma("unroll") for (int j = 0; j < 8; ++j) {                          \
      smem[(set) * 4096 + r * 512 + tx + (j << 6)] = acc[r][j]; } } }
#define RED_ADD(set) {                                                       \
  _Pragma("unroll") for (int r = 0; r < 8; ++r) {                            \
    _Pragma("unroll") for (int j = 0; j < 8; ++j) {                          \
      acc[r][j] += smem[(set) * 4096 + r * 512 + tx + (j << 6)]; } } }

  if (tz == 4) { RED_WRITE(0) } else if (tz == 5) { RED_WRITE(1) }
  __syncthreads();
  if (tz == 0) { RED_ADD(0) } else if (tz == 1) { RED_ADD(1) }
  __syncthreads();
  if (tz == 6) { RED_WRITE(0) } else if (tz == 7) { RED_WRITE(1) }
  __syncthreads();
  if (tz == 2) { RED_ADD(0) } else if (tz == 3) { RED_ADD(1) }
  __syncthreads();
  if (tz == 2) { RED_WRITE(0) } else if (tz == 3) { RED_WRITE(1) }
  __syncthreads();
  if (tz == 0) { RED_ADD(0) } else if (tz == 1) { RED_ADD(1) }
  __syncthreads();
  if (tz == 1) { RED_WRITE(0) }
  __syncthreads();

  if (tz == 0) {
    RED_ADD(0)   // acc now holds full h1 (pre-bias) for 8 rows x this lane's 8 cols
    const float4* b1v = (const float4*)b1;
    const float4* w2v = (const float4*)W2;
    const float4 blo = b1v[tx * 2], bhi = b1v[tx * 2 + 1];
    const float4 wlo = w2v[tx * 2], whi = w2v[tx * 2 + 1];
#pragma unroll
    for (int r = 0; r < 8; ++r) {
      float s = fmaxf(acc[r][0] + blo.x, 0.f) * wlo.x
              + fmaxf(acc[r][1] + blo.y, 0.f) * wlo.y
              + fmaxf(acc[r][2] + blo.z, 0.f) * wlo.z
              + fmaxf(acc[r][3] + blo.w, 0.f) * wlo.w
              + fmaxf(acc[r][4] + bhi.x, 0.f) * whi.x
              + fmaxf(acc[r][5] + bhi.y, 0.f) * whi.y
              + fmaxf(acc[r][6] + bhi.z, 0.f) * whi.z
              + fmaxf(acc[r][7] + bhi.w, 0.f) * whi.w;
#pragma unroll
      for (int off = 32; off > 0; off >>= 1) s += __shfl_down(s, off);
      if (tx == 0) {
        float x  = s + b2[0];
        float mg = 1.0f / (1.0f + __expf(-x));
        mix_out[r0 + r] = mg;
        l1m_out[r0 + r] = logf(1.0f - mg);
      }
    }
  }
#undef RED_WRITE
#undef RED_ADD
}

// ---------------- Kernel C: bulk output  out = logits + (log(1-m) - L) ----------------
__global__ __launch_bounds__(256) void k_out(
    const float* __restrict__ logits,
    const float* __restrict__ L,
    const float* __restrict__ l1m,
    float* __restrict__ out)
{
  const int n   = (int)gridDim.y - 1 - (int)blockIdx.y;   // reverse rows: L3 tail reuse
  const int seg = blockIdx.x;
  const size_t base = (size_t)n * V_DIM + (size_t)seg * 8000;
  const float4* in4 = (const float4*)(logits + base);
  float4*      out4 = (float4*)(out + base);
  const float c = l1m[n] - L[n];
  for (int i = threadIdx.x; i < 2000; i += 256) {
    float4 v = in4[i];
    float4 o; o.x = v.x + c; o.y = v.y + c; o.z = v.z + c; o.w = v.w + c;
    out4[i] = o;
  }
}

// ---------------- Kernel D: fixup at the K token positions (duplicate-safe) -----------
__global__ __launch_bounds__(256) void k_fixup(
    const float* __restrict__ logits,
    const int* __restrict__ tok,
    const float* __restrict__ sd,
    const float* __restrict__ L,
    const float* __restrict__ mix,
    float* __restrict__ out)
{
  const int t = blockIdx.x * 256 + threadIdx.x;   // < N*K
  const int n = t >> 4, k = t & 15;
  const int my = tok[n * K_TOP + k];
  float e = 0.0f;
  bool first = true;
#pragma unroll
  for (int k2 = 0; k2 < K_TOP; ++k2) {
    const int i2 = tok[n * K_TOP + k2];
    if (i2 == my) { e += sd[n * K_TOP + k2]; if (k2 < k) first = false; }
  }
  if (first) {   // exactly one writer per distinct (n, vocab index)
    const float x = logits[(size_t)n * V_DIM + my];
    const float p = __expf(x - L[n]);
    const float m = mix[n];
    out[(size_t)n * V_DIM + my] = logf((1.0f - m) * p + m * e);
  }
}

extern "C" void kernel_launch(void* const* d_in, const int* in_sizes, int n_in,
                              void* d_out, int out_size, void* d_ws, size_t ws_size,
                              hipStream_t stream)
{
  const float* hidden = (const float*)d_in[0];
  const float* logits = (const float*)d_in[1];
  const float* dist   = (const float*)d_in[2];
  const float* sh     = (const float*)d_in[3];
  const int*   tok    = (const int*)d_in[4];
  const float* bwW    = (const float*)d_in[5];
  const float* bwb    = (const float*)d_in[6];
  const float* W1     = (const float*)d_in[7];
  const float* b1     = (const float*)d_in[8];
  const float* W2     = (const float*)d_in[9];
  const float* b2     = (const float*)d_in[10];
  float* out = (float*)d_out;
  float* ws  = (float*)d_ws;

  float* sdp = ws;                        // N*K  sparse_dist
  float* Lp  = ws + N_ROWS * K_TOP;       // N    logsumexp (max + log sum)
  float* mxp = Lp + N_ROWS;               // N    mixing
  float* l1p = mxp + N_ROWS;              // N    log(1 - mixing)

  k_rowstats<<<N_ROWS, 256, 0, stream>>>(hidden, logits, dist, sh, bwW, bwb, sdp, Lp);
  k_mlp<<<N_ROWS / 8, 512, 0, stream>>>(hidden, sh, sdp, W1, b1, W2, b2, mxp, l1p);
  k_out<<<dim3(4, N_ROWS), 256, 0, stream>>>(logits, Lp, l1p, out);
  k_fixup<<<(N_ROWS * K_TOP) / 256, 256, 0, stream>>>(logits, tok, sdp, Lp, mxp, out);
}

// Round 2
// 167.400 us; speedup vs baseline: 1.3526x; 1.3526x over previous
//
#include <hip/hip_runtime.h>
#include <math.h>

#define N_ROWS 2048
#define D_DIM  512
#define V_DIM  32000
#define K_TOP  16

// ================= K1: fused bandwidth/sparse-softmax + mixing-weight MLP =================
// 512 threads = (q 0..127 float4-col) x (kg 0..3 k-group). 8 rows per block, 256 blocks.
__global__ __launch_bounds__(512) void k_mlp(
    const float* __restrict__ hidden,
    const float* __restrict__ sh,
    const float* __restrict__ dist,
    const float* __restrict__ bwW,
    const float* __restrict__ bwb,
    const float* __restrict__ W1,
    const float* __restrict__ b1,
    const float* __restrict__ W2,
    const float* __restrict__ b2,
    float* __restrict__ sd_out,
    float* __restrict__ mix_out,
    float* __restrict__ l1m_out)
{
  __shared__ float smem[8192];            // 32 KB: A tile [8][1024] -> reduce buf
  __shared__ float4 psum[4][128];         // 8 KB scratch for cross-kg sums
  __shared__ float sd_l[8][K_TOP];
  __shared__ float redb[2];
  const int tid = threadIdx.x;
  const int q   = tid & 127;
  const int kg  = tid >> 7;
  const int tx  = tid & 63;
  const int tz  = tid >> 6;
  const int r0  = blockIdx.x * 8;

  const float4* bwW4 = (const float4*)bwW;

  // ---------- Phase A: per row, read sh ONCE -> bandwidth dot -> sd -> merged -> A tile ----
  for (int r = 0; r < 8; ++r) {
    const int row = r0 + r;
    const float4* sh4 = (const float4*)(sh + (size_t)row * (K_TOP * D_DIM));
    float4 shv[4];
    float4 s4 = make_float4(0.f, 0.f, 0.f, 0.f);
#pragma unroll
    for (int kk = 0; kk < 4; ++kk) {                 // k = kk*4 + kg
      shv[kk] = sh4[(kk * 4 + kg) * 128 + q];
      s4.x += shv[kk].x; s4.y += shv[kk].y; s4.z += shv[kk].z; s4.w += shv[kk].w;
    }
    psum[kg][q] = s4;
    __syncthreads();
    if (kg == 0) {                                   // waves 0..1 exactly
      float4 m4;
      m4.x = psum[0][q].x + psum[1][q].x + psum[2][q].x + psum[3][q].x;
      m4.y = psum[0][q].y + psum[1][q].y + psum[2][q].y + psum[3][q].y;
      m4.z = psum[0][q].z + psum[1][q].z + psum[2][q].z + psum[3][q].z;
      m4.w = psum[0][q].w + psum[1][q].w + psum[2][q].w + psum[3][q].w;
      const float4 h4 = ((const float4*)(hidden + (size_t)row * D_DIM))[q];
      ((float4*)smem)[r * 256 + q] = h4;             // A tile, hidden half
      const float4 w0 = bwW4[q];
      const float4 w1 = bwW4[128 + q];
      float bp = h4.x * w0.x + h4.y * w0.y + h4.z * w0.z + h4.w * w0.w
               + 0.0625f * (m4.x * w1.x + m4.y * w1.y + m4.z * w1.z + m4.w * w1.w);
#pragma unroll
      for (int off = 32; off > 0; off >>= 1) bp += __shfl_down(bp, off);
      if ((tid & 63) == 0) redb[tid >> 6] = bp;
    }
    __syncthreads();
    if (tid == 0) {
      const float dot = redb[0] + redb[1] + bwb[0];
      const float bw  = 1.0f / (1.0f + __expf(-dot));
      float sc[K_TOP];
      float mx = -1e30f;
#pragma unroll
      for (int k = 0; k < K_TOP; ++k) {
        sc[k] = -dist[row * K_TOP + k] / bw;
        mx = fmaxf(mx, sc[k]);
      }
      float ssum = 0.0f;
#pragma unroll
      for (int k = 0; k < K_TOP; ++k) { sc[k] = __expf(sc[k] - mx); ssum += sc[k]; }
      const float inv = 1.0f / ssum;
#pragma unroll
      for (int k = 0; k < K_TOP; ++k) {
        const float v = sc[k] * inv;
        sd_l[r][k] = v;
        sd_out[row * K_TOP + k] = v;
      }
    }
    __syncthreads();
    float4 mg = make_float4(0.f, 0.f, 0.f, 0.f);
#pragma unroll
    for (int kk = 0; kk < 4; ++kk) {
      const float s = sd_l[r][kk * 4 + kg];
      mg.x = fmaf(s, shv[kk].x, mg.x); mg.y = fmaf(s, shv[kk].y, mg.y);
      mg.z = fmaf(s, shv[kk].z, mg.z); mg.w = fmaf(s, shv[kk].w, mg.w);
    }
    psum[kg][q] = mg;
    __syncthreads();
    if (kg == 0) {
      float4 m4;
      m4.x = psum[0][q].x + psum[1][q].x + psum[2][q].x + psum[3][q].x;
      m4.y = psum[0][q].y + psum[1][q].y + psum[2][q].y + psum[3][q].y;
      m4.z = psum[0][q].z + psum[1][q].z + psum[2][q].z + psum[3][q].z;
      m4.w = psum[0][q].w + psum[1][q].w + psum[2][q].w + psum[3][q].w;
      ((float4*)smem)[r * 256 + 128 + q] = m4;       // A tile, merged half
    }
    __syncthreads();
  }

  // ---------- Phase B: GEMM [8x1024] @ [1024x512], 8-way k-split, swizzled LDS reduce ----
  float acc[8][8];
#pragma unroll
  for (int r = 0; r < 8; ++r)
#pragma unroll
    for (int j = 0; j < 8; ++j) acc[r][j] = 0.0f;

  const float4* A4 = (const float4*)smem;
  const float4* W4 = (const float4*)W1;
  const int kbase = tz * 128;
  for (int kk = 0; kk < 128; kk += 4) {
    const int k0 = kbase + kk;
    float4 a[8];
#pragma unroll
    for (int r = 0; r < 8; ++r) a[r] = A4[r * 256 + (k0 >> 2)];
#pragma unroll
    for (int dk = 0; dk < 4; ++dk) {
      const int k = k0 + dk;
      const float4 wlo = W4[k * 128 + tx * 2];
      const float4 whi = W4[k * 128 + tx * 2 + 1];
#pragma unroll
      for (int r = 0; r < 8; ++r) {
        const float av = (dk == 0) ? a[r].x : (dk == 1) ? a[r].y
                       : (dk == 2) ? a[r].z : a[r].w;
        acc[r][0] = fmaf(av, wlo.x, acc[r][0]);
        acc[r][1] = fmaf(av, wlo.y, acc[r][1]);
        acc[r][2] = fmaf(av, wlo.z, acc[r][2]);
        acc[r][3] = fmaf(av, wlo.w, acc[r][3]);
        acc[r][4] = fmaf(av, whi.x, acc[r][4]);
        acc[r][5] = fmaf(av, whi.y, acc[r][5]);
        acc[r][6] = fmaf(av, whi.z, acc[r][6]);
        acc[r][7] = fmaf(av, whi.w, acc[r][7]);
      }
    }
  }
  __syncthreads();

#define RED_WRITE(set) {                                                     \
  _Pragma("unroll") for (int r = 0; r < 8; ++r) {                            \
    _Pragma("unroll") for (int j = 0; j < 8; ++j) {                          \
      smem[(set) * 4096 + r * 512 + tx + (j << 6)] = acc[r][j]; } } }
#define RED_ADD(set) {                                                       \
  _Pragma("unroll") for (int r = 0; r < 8; ++r) {                            \
    _Pragma("unroll") for (int j = 0; j < 8; ++j) {                          \
      acc[r][j] += smem[(set) * 4096 + r * 512 + tx + (j << 6)]; } } }

  if (tz == 4) { RED_WRITE(0) } else if (tz == 5) { RED_WRITE(1) }
  __syncthreads();
  if (tz == 0) { RED_ADD(0) } else if (tz == 1) { RED_ADD(1) }
  __syncthreads();
  if (tz == 6) { RED_WRITE(0) } else if (tz == 7) { RED_WRITE(1) }
  __syncthreads();
  if (tz == 2) { RED_ADD(0) } else if (tz == 3) { RED_ADD(1) }
  __syncthreads();
  if (tz == 2) { RED_WRITE(0) } else if (tz == 3) { RED_WRITE(1) }
  __syncthreads();
  if (tz == 0) { RED_ADD(0) } else if (tz == 1) { RED_ADD(1) }
  __syncthreads();
  if (tz == 1) { RED_WRITE(0) }
  __syncthreads();

  if (tz == 0) {
    RED_ADD(0)
    const float4* b1v = (const float4*)b1;
    const float4* w2v = (const float4*)W2;
    const float4 blo = b1v[tx * 2], bhi = b1v[tx * 2 + 1];
    const float4 wlo = w2v[tx * 2], whi = w2v[tx * 2 + 1];
#pragma unroll
    for (int r = 0; r < 8; ++r) {
      float s = fmaxf(acc[r][0] + blo.x, 0.f) * wlo.x
              + fmaxf(acc[r][1] + blo.y, 0.f) * wlo.y
              + fmaxf(acc[r][2] + blo.z, 0.f) * wlo.z
              + fmaxf(acc[r][3] + blo.w, 0.f) * wlo.w
              + fmaxf(acc[r][4] + bhi.x, 0.f) * whi.x
              + fmaxf(acc[r][5] + bhi.y, 0.f) * whi.y
              + fmaxf(acc[r][6] + bhi.z, 0.f) * whi.z
              + fmaxf(acc[r][7] + bhi.w, 0.f) * whi.w;
#pragma unroll
      for (int off = 32; off > 0; off >>= 1) s += __shfl_down(s, off);
      if (tx == 0) {
        const float x  = s + b2[0];
        const float mg = 1.0f / (1.0f + __expf(-x));
        mix_out[r0 + r] = mg;
        l1m_out[r0 + r] = logf(1.0f - mg);
      }
    }
  }
#undef RED_WRITE
#undef RED_ADD
}

// ================= K2: fused logsumexp + bulk output + token fixup =================
// One block per row; 1024 threads; row (8000 float4) register-cached: logits read ONCE.
__global__ __launch_bounds__(1024) void k_out(
    const float* __restrict__ logits,
    const float* __restrict__ sd,
    const float* __restrict__ mix,
    const float* __restrict__ l1m,
    const int* __restrict__ tok,
    float* __restrict__ out)
{
  const int n   = blockIdx.x;
  const int tid = threadIdx.x;
  __shared__ float Ms[16], Ss[16];
  __shared__ float cSh, LSh;

  const float4* in4 = (const float4*)(logits + (size_t)n * V_DIM);
  float4*      out4 = (float4*)(out + (size_t)n * V_DIM);

  float4 v[8];
  float tmax = -1e30f;
#pragma unroll
  for (int i = 0; i < 8; ++i) {
    const int idx = tid + (i << 10);
    if (idx < 8000) v[i] = in4[idx];
    else            v[i] = make_float4(-1e30f, -1e30f, -1e30f, -1e30f);
    tmax = fmaxf(tmax, fmaxf(fmaxf(v[i].x, v[i].y), fmaxf(v[i].z, v[i].w)));
  }
  float tsum = 0.0f;
#pragma unroll
  for (int i = 0; i < 8; ++i) {
    tsum += __expf(v[i].x - tmax) + __expf(v[i].y - tmax)
          + __expf(v[i].z - tmax) + __expf(v[i].w - tmax);
  }
  // wave reduce (M,S)
#pragma unroll
  for (int off = 32; off > 0; off >>= 1) {
    const float M2 = __shfl_xor(tmax, off);
    const float S2 = __shfl_xor(tsum, off);
    const float Mn = fmaxf(tmax, M2);
    tsum = tsum * __expf(tmax - Mn) + S2 * __expf(M2 - Mn);
    tmax = Mn;
  }
  if ((tid & 63) == 0) { Ms[tid >> 6] = tmax; Ss[tid >> 6] = tsum; }
  __syncthreads();
  if (tid == 0) {
    float M = Ms[0], S = Ss[0];
#pragma unroll
    for (int w = 1; w < 16; ++w) {
      const float Mn = fmaxf(M, Ms[w]);
      S = S * __expf(M - Mn) + Ss[w] * __expf(Ms[w] - Mn);
      M = Mn;
    }
    const float L = M + logf(S);
    LSh = L;
    cSh = l1m[n] - L;
  }
  __syncthreads();
  const float c = cSh;
#pragma unroll
  for (int i = 0; i < 8; ++i) {
    const int idx = tid + (i << 10);
    if (idx < 8000) {
      float4 o;
      o.x = v[i].x + c; o.y = v[i].y + c; o.z = v[i].z + c; o.w = v[i].w + c;
      out4[idx] = o;
    }
  }
  __syncthreads();   // drains vmcnt: bulk stores complete before fixup overwrites
  if (tid < K_TOP) {
    const int k  = tid;
    const int my = tok[n * K_TOP + k];
    float e = 0.0f;
    bool first = true;
#pragma unroll
    for (int k2 = 0; k2 < K_TOP; ++k2) {
      const int i2 = tok[n * K_TOP + k2];
      if (i2 == my) { e += sd[n * K_TOP + k2]; if (k2 < k) first = false; }
    }
    if (first) {
      const float x = logits[(size_t)n * V_DIM + my];
      const float m = mix[n];
      const float p = __expf(x - LSh);
      out[(size_t)n * V_DIM + my] = logf((1.0f - m) * p + m * e);
    }
  }
}

extern "C" void kernel_launch(void* const* d_in, const int* in_sizes, int n_in,
                              void* d_out, int out_size, void* d_ws, size_t ws_size,
                              hipStream_t stream)
{
  const float* hidden = (const float*)d_in[0];
  const float* logits = (const float*)d_in[1];
  const float* dist   = (const float*)d_in[2];
  const float* sh     = (const float*)d_in[3];
  const int*   tok    = (const int*)d_in[4];
  const float* bwW    = (const float*)d_in[5];
  const float* bwb    = (const float*)d_in[6];
  const float* W1     = (const float*)d_in[7];
  const float* b1     = (const float*)d_in[8];
  const float* W2     = (const float*)d_in[9];
  const float* b2     = (const float*)d_in[10];
  float* out = (float*)d_out;
  float* ws  = (float*)d_ws;

  float* sdp = ws;                        // N*K  sparse_dist
  float* mxp = ws + N_ROWS * K_TOP;       // N    mixing
  float* l1p = mxp + N_ROWS;              // N    log(1 - mixing)

  k_mlp<<<N_ROWS / 8, 512, 0, stream>>>(hidden, sh, dist, bwW, bwb,
                                        W1, b1, W2, b2, sdp, mxp, l1p);
  k_out<<<N_ROWS, 1024, 0, stream>>>(logits, sdp, mxp, l1p, tok, out);
}

// Round 3
// 149.819 us; speedup vs baseline: 1.5113x; 1.1173x over previous
//
#include <hip/hip_runtime.h>
#include <math.h>

#define N_ROWS 2048
#define D_DIM  512
#define V_DIM  32000
#define K_TOP  16

typedef float f32x4 __attribute__((ext_vector_type(4)));

// ================= K1: fused bandwidth/sparse-softmax + mixing-weight MLP =================
// 512 threads = 8 waves; phase A: wave w owns row r0+w (no barriers);
// phase B: 64 col-lanes (tx) x 8 k-groups (tz), verified GEMM + LDS reduce tree.
__global__ __launch_bounds__(512) void k_mlp(
    const float* __restrict__ hidden,
    const float* __restrict__ sh,
    const float* __restrict__ dist,
    const float* __restrict__ bwW,
    const float* __restrict__ bwb,
    const float* __restrict__ W1,
    const float* __restrict__ b1,
    const float* __restrict__ W2,
    const float* __restrict__ b2,
    float* __restrict__ sd_out,
    float* __restrict__ mix_out,
    float* __restrict__ l1m_out)
{
  __shared__ float smem[8192];            // 32 KB: A tile [8][1024] -> reduce buf
  const int tid = threadIdx.x;
  const int tx  = tid & 63;               // lane
  const int tz  = tid >> 6;               // wave
  const int r0  = blockIdx.x * 8;

  // ---------- Phase A: wave-per-row, sh read once (2nd pass hits cache) ----------
  {
    const int lane = tx;
    const int row  = r0 + tz;
    const float4* sh4  = (const float4*)(sh + (size_t)row * (K_TOP * D_DIM));
    const float4* hid4 = (const float4*)(hidden + (size_t)row * D_DIM);
    const float4* bwW4 = (const float4*)bwW;

    float4 msA = make_float4(0.f,0.f,0.f,0.f), msB = make_float4(0.f,0.f,0.f,0.f);
#pragma unroll
    for (int k = 0; k < K_TOP; ++k) {
      const float4 a = sh4[k * 128 + lane];
      const float4 b = sh4[k * 128 + 64 + lane];
      msA.x += a.x; msA.y += a.y; msA.z += a.z; msA.w += a.w;
      msB.x += b.x; msB.y += b.y; msB.z += b.z; msB.w += b.w;
    }
    const float4 h4a = hid4[lane], h4b = hid4[64 + lane];
    float4* A4w = (float4*)smem;
    A4w[tz * 256 + lane]      = h4a;            // A tile: hidden half (cols 0..511)
    A4w[tz * 256 + 64 + lane] = h4b;
    const float4 wa = bwW4[lane],       wb = bwW4[64 + lane];
    const float4 wc = bwW4[128 + lane], wd = bwW4[192 + lane];
    float bp = h4a.x*wa.x + h4a.y*wa.y + h4a.z*wa.z + h4a.w*wa.w
             + h4b.x*wb.x + h4b.y*wb.y + h4b.z*wb.z + h4b.w*wb.w
             + 0.0625f * (msA.x*wc.x + msA.y*wc.y + msA.z*wc.z + msA.w*wc.w
                        + msB.x*wd.x + msB.y*wd.y + msB.z*wd.z + msB.w*wd.w);
#pragma unroll
    for (int off = 32; off > 0; off >>= 1) bp += __shfl_down(bp, off);
    bp = __shfl(bp, 0);
    const float bw = 1.0f / (1.0f + __expf(-(bp + bwb[0])));

    // all lanes redundantly compute the 16-way sparse softmax (registers only)
    float sc[K_TOP];
    float mx = -1e30f;
#pragma unroll
    for (int k = 0; k < K_TOP; ++k) {
      sc[k] = -dist[row * K_TOP + k] / bw;
      mx = fmaxf(mx, sc[k]);
    }
    float ssum = 0.0f;
#pragma unroll
    for (int k = 0; k < K_TOP; ++k) { sc[k] = __expf(sc[k] - mx); ssum += sc[k]; }
    const float inv = 1.0f / ssum;
#pragma unroll
    for (int k = 0; k < K_TOP; ++k) sc[k] *= inv;
    if (lane == 0) {
#pragma unroll
      for (int k = 0; k < K_TOP; ++k) sd_out[row * K_TOP + k] = sc[k];
    }

    // merged = sum_k sd[k] * sh[k][:]  (re-read sh; L1/L2-resident)
    float4 mgA = make_float4(0.f,0.f,0.f,0.f), mgB = make_float4(0.f,0.f,0.f,0.f);
#pragma unroll
    for (int k = 0; k < K_TOP; ++k) {
      const float4 a = sh4[k * 128 + lane];
      const float4 b = sh4[k * 128 + 64 + lane];
      mgA.x = fmaf(sc[k], a.x, mgA.x); mgA.y = fmaf(sc[k], a.y, mgA.y);
      mgA.z = fmaf(sc[k], a.z, mgA.z); mgA.w = fmaf(sc[k], a.w, mgA.w);
      mgB.x = fmaf(sc[k], b.x, mgB.x); mgB.y = fmaf(sc[k], b.y, mgB.y);
      mgB.z = fmaf(sc[k], b.z, mgB.z); mgB.w = fmaf(sc[k], b.w, mgB.w);
    }
    A4w[tz * 256 + 128 + lane] = mgA;           // A tile: merged half (cols 512..1023)
    A4w[tz * 256 + 192 + lane] = mgB;
  }
  __syncthreads();

  // ---------- Phase B: GEMM [8x1024] @ [1024x512], 8-way k-split, swizzled LDS reduce ----
  float acc[8][8];
#pragma unroll
  for (int r = 0; r < 8; ++r)
#pragma unroll
    for (int j = 0; j < 8; ++j) acc[r][j] = 0.0f;

  const float4* A4 = (const float4*)smem;
  const float4* W4 = (const float4*)W1;
  const int kbase = tz * 128;
  for (int kk = 0; kk < 128; kk += 4) {
    const int k0 = kbase + kk;
    float4 a[8];
#pragma unroll
    for (int r = 0; r < 8; ++r) a[r] = A4[r * 256 + (k0 >> 2)];
#pragma unroll
    for (int dk = 0; dk < 4; ++dk) {
      const int k = k0 + dk;
      const float4 wlo = W4[k * 128 + tx * 2];
      const float4 whi = W4[k * 128 + tx * 2 + 1];
#pragma unroll
      for (int r = 0; r < 8; ++r) {
        const float av = (dk == 0) ? a[r].x : (dk == 1) ? a[r].y
                       : (dk == 2) ? a[r].z : a[r].w;
        acc[r][0] = fmaf(av, wlo.x, acc[r][0]);
        acc[r][1] = fmaf(av, wlo.y, acc[r][1]);
        acc[r][2] = fmaf(av, wlo.z, acc[r][2]);
        acc[r][3] = fmaf(av, wlo.w, acc[r][3]);
        acc[r][4] = fmaf(av, whi.x, acc[r][4]);
        acc[r][5] = fmaf(av, whi.y, acc[r][5]);
        acc[r][6] = fmaf(av, whi.z, acc[r][6]);
        acc[r][7] = fmaf(av, whi.w, acc[r][7]);
      }
    }
  }
  __syncthreads();

#define RED_WRITE(set) {                                                     \
  _Pragma("unroll") for (int r = 0; r < 8; ++r) {                            \
    _Pragma("unroll") for (int j = 0; j < 8; ++j) {                          \
      smem[(set) * 4096 + r * 512 + tx + (j << 6)] = acc[r][j]; } } }
#define RED_ADD(set) {                                                       \
  _Pragma("unroll") for (int r = 0; r < 8; ++r) {                            \
    _Pragma("unroll") for (int j = 0; j < 8; ++j) {                          \
      acc[r][j] += smem[(set) * 4096 + r * 512 + tx + (j << 6)]; } } }

  if (tz == 4) { RED_WRITE(0) } else if (tz == 5) { RED_WRITE(1) }
  __syncthreads();
  if (tz == 0) { RED_ADD(0) } else if (tz == 1) { RED_ADD(1) }
  __syncthreads();
  if (tz == 6) { RED_WRITE(0) } else if (tz == 7) { RED_WRITE(1) }
  __syncthreads();
  if (tz == 2) { RED_ADD(0) } else if (tz == 3) { RED_ADD(1) }
  __syncthreads();
  if (tz == 2) { RED_WRITE(0) } else if (tz == 3) { RED_WRITE(1) }
  __syncthreads();
  if (tz == 0) { RED_ADD(0) } else if (tz == 1) { RED_ADD(1) }
  __syncthreads();
  if (tz == 1) { RED_WRITE(0) }
  __syncthreads();

  if (tz == 0) {
    RED_ADD(0)
    const float4* b1v = (const float4*)b1;
    const float4* w2v = (const float4*)W2;
    const float4 blo = b1v[tx * 2], bhi = b1v[tx * 2 + 1];
    const float4 wlo = w2v[tx * 2], whi = w2v[tx * 2 + 1];
#pragma unroll
    for (int r = 0; r < 8; ++r) {
      float s = fmaxf(acc[r][0] + blo.x, 0.f) * wlo.x
              + fmaxf(acc[r][1] + blo.y, 0.f) * wlo.y
              + fmaxf(acc[r][2] + blo.z, 0.f) * wlo.z
              + fmaxf(acc[r][3] + blo.w, 0.f) * wlo.w
              + fmaxf(acc[r][4] + bhi.x, 0.f) * whi.x
              + fmaxf(acc[r][5] + bhi.y, 0.f) * whi.y
              + fmaxf(acc[r][6] + bhi.z, 0.f) * whi.z
              + fmaxf(acc[r][7] + bhi.w, 0.f) * whi.w;
#pragma unroll
      for (int off = 32; off > 0; off >>= 1) s += __shfl_down(s, off);
      if (tx == 0) {
        const float x  = s + b2[0];
        const float mg = 1.0f / (1.0f + __expf(-x));
        mix_out[r0 + r] = mg;
        l1m_out[r0 + r] = logf(1.0f - mg);
      }
    }
  }
#undef RED_WRITE
#undef RED_ADD
}

// ================= K2: fused logsumexp + bulk output + token fixup =================
// One block per row; 1024 threads; row (8000 float4) register-cached; NT load/store;
// fixup values prefetched at block start.
__global__ __launch_bounds__(1024) void k_out(
    const float* __restrict__ logits,
    const float* __restrict__ sd,
    const float* __restrict__ mix,
    const float* __restrict__ l1m,
    const int* __restrict__ tok,
    float* __restrict__ out)
{
  const int n   = blockIdx.x;
  const int tid = threadIdx.x;
  __shared__ float Ms[16], Ss[16];
  __shared__ float cSh, LSh;

  // ---- fixup prefetch (lanes 0..15 of wave 0): hide the dependent scalar loads ----
  float fx_x = 0.f, fx_e = 0.f, fx_m = 0.f;
  int fx_my = 0; bool fx_first = false;
  if (tid < K_TOP) {
    fx_my = tok[n * K_TOP + tid];
    fx_first = true;
#pragma unroll
    for (int k2 = 0; k2 < K_TOP; ++k2) {
      const int i2 = tok[n * K_TOP + k2];
      if (i2 == fx_my) { fx_e += sd[n * K_TOP + k2]; if (k2 < tid) fx_first = false; }
    }
    fx_x = logits[(size_t)n * V_DIM + fx_my];
    fx_m = mix[n];
  }

  const f32x4* in4 = (const f32x4*)(logits + (size_t)n * V_DIM);
  f32x4*      out4 = (f32x4*)(out + (size_t)n * V_DIM);

  f32x4 v[8];
  float tmax = -1e30f;
#pragma unroll
  for (int i = 0; i < 8; ++i) {
    const int idx = tid + (i << 10);
    if (idx < 8000) v[i] = __builtin_nontemporal_load(in4 + idx);
    else { v[i].x = -1e30f; v[i].y = -1e30f; v[i].z = -1e30f; v[i].w = -1e30f; }
    tmax = fmaxf(tmax, fmaxf(fmaxf(v[i].x, v[i].y), fmaxf(v[i].z, v[i].w)));
  }
  float tsum = 0.0f;
#pragma unroll
  for (int i = 0; i < 8; ++i) {
    tsum += __expf(v[i].x - tmax) + __expf(v[i].y - tmax)
          + __expf(v[i].z - tmax) + __expf(v[i].w - tmax);
  }
#pragma unroll
  for (int off = 32; off > 0; off >>= 1) {
    const float M2 = __shfl_xor(tmax, off);
    const float S2 = __shfl_xor(tsum, off);
    const float Mn = fmaxf(tmax, M2);
    tsum = tsum * __expf(tmax - Mn) + S2 * __expf(M2 - Mn);
    tmax = Mn;
  }
  if ((tid & 63) == 0) { Ms[tid >> 6] = tmax; Ss[tid >> 6] = tsum; }
  __syncthreads();
  if (tid == 0) {
    float M = Ms[0], S = Ss[0];
#pragma unroll
    for (int w = 1; w < 16; ++w) {
      const float Mn = fmaxf(M, Ms[w]);
      S = S * __expf(M - Mn) + Ss[w] * __expf(Ms[w] - Mn);
      M = Mn;
    }
    const float L = M + logf(S);
    LSh = L;
    cSh = l1m[n] - L;
  }
  __syncthreads();
  const float c = cSh;
#pragma unroll
  for (int i = 0; i < 8; ++i) {
    const int idx = tid + (i << 10);
    if (idx < 8000) {
      f32x4 o;
      o.x = v[i].x + c; o.y = v[i].y + c; o.z = v[i].z + c; o.w = v[i].w + c;
      __builtin_nontemporal_store(o, out4 + idx);
    }
  }
  __syncthreads();   // drains vmcnt: bulk stores complete before fixup overwrites
  if (tid < K_TOP && fx_first) {
    const float p = __expf(fx_x - LSh);
    const float r = logf((1.0f - fx_m) * p + fx_m * fx_e);
    __builtin_nontemporal_store(r, out + (size_t)n * V_DIM + fx_my);
  }
}

extern "C" void kernel_launch(void* const* d_in, const int* in_sizes, int n_in,
                              void* d_out, int out_size, void* d_ws, size_t ws_size,
                              hipStream_t stream)
{
  const float* hidden = (const float*)d_in[0];
  const float* logits = (const float*)d_in[1];
  const float* dist   = (const float*)d_in[2];
  const float* sh     = (const float*)d_in[3];
  const int*   tok    = (const int*)d_in[4];
  const float* bwW    = (const float*)d_in[5];
  const float* bwb    = (const float*)d_in[6];
  const float* W1     = (const float*)d_in[7];
  const float* b1     = (const float*)d_in[8];
  const float* W2     = (const float*)d_in[9];
  const float* b2     = (const float*)d_in[10];
  float* out = (float*)d_out;
  float* ws  = (float*)d_ws;

  float* sdp = ws;                        // N*K  sparse_dist
  float* mxp = ws + N_ROWS * K_TOP;       // N    mixing
  float* l1p = mxp + N_ROWS;              // N    log(1 - mixing)

  k_mlp<<<N_ROWS / 8, 512, 0, stream>>>(hidden, sh, dist, bwW, bwb,
                                        W1, b1, W2, b2, sdp, mxp, l1p);
  k_out<<<N_ROWS, 1024, 0, stream>>>(logits, sdp, mxp, l1p, tok, out);
}

// Round 4
// 140.686 us; speedup vs baseline: 1.6094x; 1.0649x over previous
//
#include <hip/hip_runtime.h>
#include <math.h>

#define N_ROWS 2048
#define D_DIM  512
#define V_DIM  32000
#define K_TOP  16

typedef float f32x4 __attribute__((ext_vector_type(4)));

// ================= K1: fused bandwidth/sparse-softmax + mixing-weight MLP =================
// 512 threads = 8 waves; phase A: wave w owns row r0+w, sh row slice REGISTER-CACHED
// (read from HBM exactly once); phase B: 64 col-lanes x 8 k-groups GEMM + LDS reduce tree.
__global__ __launch_bounds__(512, 2) void k_mlp(
    const float* __restrict__ hidden,
    const float* __restrict__ sh,
    const float* __restrict__ dist,
    const float* __restrict__ bwW,
    const float* __restrict__ bwb,
    const float* __restrict__ W1,
    const float* __restrict__ b1,
    const float* __restrict__ W2,
    const float* __restrict__ b2,
    float* __restrict__ sd_out,
    float* __restrict__ mix_out,
    float* __restrict__ l1m_out)
{
  __shared__ float smem[8192];            // 32 KB: A tile [8][1024] -> reduce buf
  const int tid = threadIdx.x;
  const int tx  = tid & 63;               // lane
  const int tz  = tid >> 6;               // wave
  const int r0  = blockIdx.x * 8;

  // ---------- Phase A: wave-per-row; sh slice lives in registers ----------
  {
    const int lane = tx;
    const int row  = r0 + tz;
    const float4* sh4  = (const float4*)(sh + (size_t)row * (K_TOP * D_DIM));
    const float4* hid4 = (const float4*)(hidden + (size_t)row * D_DIM);
    const float4* bwW4 = (const float4*)bwW;

    float4 shvA[K_TOP], shvB[K_TOP];      // 128 VGPRs: this lane's slice of the whole row
#pragma unroll
    for (int k = 0; k < K_TOP; ++k) {
      shvA[k] = sh4[k * 128 + lane];
      shvB[k] = sh4[k * 128 + 64 + lane];
    }
    float dv[K_TOP];
#pragma unroll
    for (int k = 0; k < K_TOP; ++k) dv[k] = dist[row * K_TOP + k];

    float4 msA = make_float4(0.f,0.f,0.f,0.f), msB = make_float4(0.f,0.f,0.f,0.f);
#pragma unroll
    for (int k = 0; k < K_TOP; ++k) {
      msA.x += shvA[k].x; msA.y += shvA[k].y; msA.z += shvA[k].z; msA.w += shvA[k].w;
      msB.x += shvB[k].x; msB.y += shvB[k].y; msB.z += shvB[k].z; msB.w += shvB[k].w;
    }
    const float4 h4a = hid4[lane], h4b = hid4[64 + lane];
    float4* A4w = (float4*)smem;
    A4w[tz * 256 + lane]      = h4a;            // A tile: hidden half (cols 0..511)
    A4w[tz * 256 + 64 + lane] = h4b;
    const float4 wa = bwW4[lane],       wb = bwW4[64 + lane];
    const float4 wc = bwW4[128 + lane], wd = bwW4[192 + lane];
    float bp = h4a.x*wa.x + h4a.y*wa.y + h4a.z*wa.z + h4a.w*wa.w
             + h4b.x*wb.x + h4b.y*wb.y + h4b.z*wb.z + h4b.w*wb.w
             + 0.0625f * (msA.x*wc.x + msA.y*wc.y + msA.z*wc.z + msA.w*wc.w
                        + msB.x*wd.x + msB.y*wd.y + msB.z*wd.z + msB.w*wd.w);
#pragma unroll
    for (int off = 32; off > 0; off >>= 1) bp += __shfl_down(bp, off);
    bp = __shfl(bp, 0);
    const float bw = 1.0f / (1.0f + __expf(-(bp + bwb[0])));

    // all lanes redundantly compute the 16-way sparse softmax (registers only)
    float sc[K_TOP];
    float mx = -1e30f;
#pragma unroll
    for (int k = 0; k < K_TOP; ++k) {
      sc[k] = -dv[k] / bw;
      mx = fmaxf(mx, sc[k]);
    }
    float ssum = 0.0f;
#pragma unroll
    for (int k = 0; k < K_TOP; ++k) { sc[k] = __expf(sc[k] - mx); ssum += sc[k]; }
    const float inv = 1.0f / ssum;
#pragma unroll
    for (int k = 0; k < K_TOP; ++k) sc[k] *= inv;
    if (lane == 0) {
#pragma unroll
      for (int k = 0; k < K_TOP; ++k) sd_out[row * K_TOP + k] = sc[k];
    }

    // merged = sum_k sd[k] * sh[k][:]  -- straight from registers
    float4 mgA = make_float4(0.f,0.f,0.f,0.f), mgB = make_float4(0.f,0.f,0.f,0.f);
#pragma unroll
    for (int k = 0; k < K_TOP; ++k) {
      mgA.x = fmaf(sc[k], shvA[k].x, mgA.x); mgA.y = fmaf(sc[k], shvA[k].y, mgA.y);
      mgA.z = fmaf(sc[k], shvA[k].z, mgA.z); mgA.w = fmaf(sc[k], shvA[k].w, mgA.w);
      mgB.x = fmaf(sc[k], shvB[k].x, mgB.x); mgB.y = fmaf(sc[k], shvB[k].y, mgB.y);
      mgB.z = fmaf(sc[k], shvB[k].z, mgB.z); mgB.w = fmaf(sc[k], shvB[k].w, mgB.w);
    }
    A4w[tz * 256 + 128 + lane] = mgA;           // A tile: merged half (cols 512..1023)
    A4w[tz * 256 + 192 + lane] = mgB;
  }
  __syncthreads();

  // ---------- Phase B: GEMM [8x1024] @ [1024x512], 8-way k-split, swizzled LDS reduce ----
  float acc[8][8];
#pragma unroll
  for (int r = 0; r < 8; ++r)
#pragma unroll
    for (int j = 0; j < 8; ++j) acc[r][j] = 0.0f;

  const float4* A4 = (const float4*)smem;
  const float4* W4 = (const float4*)W1;
  const int kbase = tz * 128;
  for (int kk = 0; kk < 128; kk += 4) {
    const int k0 = kbase + kk;
    float4 a[8];
#pragma unroll
    for (int r = 0; r < 8; ++r) a[r] = A4[r * 256 + (k0 >> 2)];
#pragma unroll
    for (int dk = 0; dk < 4; ++dk) {
      const int k = k0 + dk;
      const float4 wlo = W4[k * 128 + tx * 2];
      const float4 whi = W4[k * 128 + tx * 2 + 1];
#pragma unroll
      for (int r = 0; r < 8; ++r) {
        const float av = (dk == 0) ? a[r].x : (dk == 1) ? a[r].y
                       : (dk == 2) ? a[r].z : a[r].w;
        acc[r][0] = fmaf(av, wlo.x, acc[r][0]);
        acc[r][1] = fmaf(av, wlo.y, acc[r][1]);
        acc[r][2] = fmaf(av, wlo.z, acc[r][2]);
        acc[r][3] = fmaf(av, wlo.w, acc[r][3]);
        acc[r][4] = fmaf(av, whi.x, acc[r][4]);
        acc[r][5] = fmaf(av, whi.y, acc[r][5]);
        acc[r][6] = fmaf(av, whi.z, acc[r][6]);
        acc[r][7] = fmaf(av, whi.w, acc[r][7]);
      }
    }
  }
  __syncthreads();

#define RED_WRITE(set) {                                                     \
  _Pragma("unroll") for (int r = 0; r < 8; ++r) {                            \
    _Pragma("unroll") for (int j = 0; j < 8; ++j) {                          \
      smem[(set) * 4096 + r * 512 + tx + (j << 6)] = acc[r][j]; } } }
#define RED_ADD(set) {                                                       \
  _Pragma("unroll") for (int r = 0; r < 8; ++r) {                            \
    _Pragma("unroll") for (int j = 0; j < 8; ++j) {                          \
      acc[r][j] += smem[(set) * 4096 + r * 512 + tx + (j << 6)]; } } }

  if (tz == 4) { RED_WRITE(0) } else if (tz == 5) { RED_WRITE(1) }
  __syncthreads();
  if (tz == 0) { RED_ADD(0) } else if (tz == 1) { RED_ADD(1) }
  __syncthreads();
  if (tz == 6) { RED_WRITE(0) } else if (tz == 7) { RED_WRITE(1) }
  __syncthreads();
  if (tz == 2) { RED_ADD(0) } else if (tz == 3) { RED_ADD(1) }
  __syncthreads();
  if (tz == 2) { RED_WRITE(0) } else if (tz == 3) { RED_WRITE(1) }
  __syncthreads();
  if (tz == 0) { RED_ADD(0) } else if (tz == 1) { RED_ADD(1) }
  __syncthreads();
  if (tz == 1) { RED_WRITE(0) }
  __syncthreads();

  if (tz == 0) {
    RED_ADD(0)
    const float4* b1v = (const float4*)b1;
    const float4* w2v = (const float4*)W2;
    const float4 blo = b1v[tx * 2], bhi = b1v[tx * 2 + 1];
    const float4 wlo = w2v[tx * 2], whi = w2v[tx * 2 + 1];
#pragma unroll
    for (int r = 0; r < 8; ++r) {
      float s = fmaxf(acc[r][0] + blo.x, 0.f) * wlo.x
              + fmaxf(acc[r][1] + blo.y, 0.f) * wlo.y
              + fmaxf(acc[r][2] + blo.z, 0.f) * wlo.z
              + fmaxf(acc[r][3] + blo.w, 0.f) * wlo.w
              + fmaxf(acc[r][4] + bhi.x, 0.f) * whi.x
              + fmaxf(acc[r][5] + bhi.y, 0.f) * whi.y
              + fmaxf(acc[r][6] + bhi.z, 0.f) * whi.z
              + fmaxf(acc[r][7] + bhi.w, 0.f) * whi.w;
#pragma unroll
      for (int off = 32; off > 0; off >>= 1) s += __shfl_down(s, off);
      if (tx == 0) {
        const float x  = s + b2[0];
        const float mg = 1.0f / (1.0f + __expf(-x));
        mix_out[r0 + r] = mg;
        l1m_out[r0 + r] = logf(1.0f - mg);
      }
    }
  }
#undef RED_WRITE
#undef RED_ADD
}

// ================= K2: fused logsumexp + bulk output + token fixup =================
// One block per row; 1024 threads; row (8000 float4) register-cached; NT load/store;
// fixup values AND l1m prefetched at block start (no dependent load on critical path).
__global__ __launch_bounds__(1024) void k_out(
    const float* __restrict__ logits,
    const float* __restrict__ sd,
    const float* __restrict__ mix,
    const float* __restrict__ l1m,
    const int* __restrict__ tok,
    float* __restrict__ out)
{
  const int n   = blockIdx.x;
  const int tid = threadIdx.x;
  __shared__ float Ms[16], Ss[16];
  __shared__ float cSh, LSh;

  // ---- prefetch (lanes 0..15 of wave 0): fixup operands + l1m, issued before bulk ----
  float fx_x = 0.f, fx_e = 0.f, fx_m = 0.f, l1m_n = 0.f;
  int fx_my = 0; bool fx_first = false;
  if (tid < K_TOP) {
    fx_my = tok[n * K_TOP + tid];
    fx_first = true;
#pragma unroll
    for (int k2 = 0; k2 < K_TOP; ++k2) {
      const int i2 = tok[n * K_TOP + k2];
      if (i2 == fx_my) { fx_e += sd[n * K_TOP + k2]; if (k2 < tid) fx_first = false; }
    }
    fx_x = logits[(size_t)n * V_DIM + fx_my];
    fx_m = mix[n];
    if (tid == 0) l1m_n = l1m[n];
  }

  const f32x4* in4 = (const f32x4*)(logits + (size_t)n * V_DIM);
  f32x4*      out4 = (f32x4*)(out + (size_t)n * V_DIM);

  f32x4 v[8];
  float tmax = -1e30f;
#pragma unroll
  for (int i = 0; i < 8; ++i) {
    const int idx = tid + (i << 10);
    if (idx < 8000) v[i] = __builtin_nontemporal_load(in4 + idx);
    else { v[i].x = -1e30f; v[i].y = -1e30f; v[i].z = -1e30f; v[i].w = -1e30f; }
    tmax = fmaxf(tmax, fmaxf(fmaxf(v[i].x, v[i].y), fmaxf(v[i].z, v[i].w)));
  }
  float tsum = 0.0f;
#pragma unroll
  for (int i = 0; i < 8; ++i) {
    tsum += __expf(v[i].x - tmax) + __expf(v[i].y - tmax)
          + __expf(v[i].z - tmax) + __expf(v[i].w - tmax);
  }
#pragma unroll
  for (int off = 32; off > 0; off >>= 1) {
    const float M2 = __shfl_xor(tmax, off);
    const float S2 = __shfl_xor(tsum, off);
    const float Mn = fmaxf(tmax, M2);
    tsum = tsum * __expf(tmax - Mn) + S2 * __expf(M2 - Mn);
    tmax = Mn;
  }
  if ((tid & 63) == 0) { Ms[tid >> 6] = tmax; Ss[tid >> 6] = tsum; }
  __syncthreads();
  if (tid == 0) {
    float M = Ms[0], S = Ss[0];
#pragma unroll
    for (int w = 1; w < 16; ++w) {
      const float Mn = fmaxf(M, Ms[w]);
      S = S * __expf(M - Mn) + Ss[w] * __expf(Ms[w] - Mn);
      M = Mn;
    }
    const float L = M + logf(S);
    LSh = L;
    cSh = l1m_n - L;
  }
  __syncthreads();
  const float c = cSh;
#pragma unroll
  for (int i = 0; i < 8; ++i) {
    const int idx = tid + (i << 10);
    if (idx < 8000) {
      f32x4 o;
      o.x = v[i].x + c; o.y = v[i].y + c; o.z = v[i].z + c; o.w = v[i].w + c;
      __builtin_nontemporal_store(o, out4 + idx);
    }
  }
  __syncthreads();   // drains vmcnt: bulk stores complete before fixup overwrites
  if (tid < K_TOP && fx_first) {
    const float p = __expf(fx_x - LSh);
    const float r = logf((1.0f - fx_m) * p + fx_m * fx_e);
    __builtin_nontemporal_store(r, out + (size_t)n * V_DIM + fx_my);
  }
}

extern "C" void kernel_launch(void* const* d_in, const int* in_sizes, int n_in,
                              void* d_out, int out_size, void* d_ws, size_t ws_size,
                              hipStream_t stream)
{
  const float* hidden = (const float*)d_in[0];
  const float* logits = (const float*)d_in[1];
  const float* dist   = (const float*)d_in[2];
  const float* sh     = (const float*)d_in[3];
  const int*   tok    = (const int*)d_in[4];
  const float* bwW    = (const float*)d_in[5];
  const float* bwb    = (const float*)d_in[6];
  const float* W1     = (const float*)d_in[7];
  const float* b1     = (const float*)d_in[8];
  const float* W2     = (const float*)d_in[9];
  const float* b2     = (const float*)d_in[10];
  float* out = (float*)d_out;
  float* ws  = (float*)d_ws;

  float* sdp = ws;                        // N*K  sparse_dist
  float* mxp = ws + N_ROWS * K_TOP;       // N    mixing
  float* l1p = mxp + N_ROWS;              // N    log(1 - mixing)

  k_mlp<<<N_ROWS / 8, 512, 0, stream>>>(hidden, sh, dist, bwW, bwb,
                                        W1, b1, W2, b2, sdp, mxp, l1p);
  k_out<<<N_ROWS, 1024, 0, stream>>>(logits, sdp, mxp, l1p, tok, out);
}